// Round 7
// baseline (453.726 us; speedup 1.0000x reference)
//
#include <hip/hip_runtime.h>

#define NBLK 256
#define NTHR 1024
#define BSZ 64
#define DIM 4096
#define MEM 5
#define MAXIT 50
#define TOL_ 0.01f
#define LAM_ 1e-4f

// float-region workspace layout (float offsets)
#define X_OFF 0
#define F_OFF (BSZ * MEM * DIM)
#define Z_OFF (2 * BSZ * MEM * DIM)
#define RP_OFF (Z_OFF + BSZ * DIM)              // residual partials [2][256]
#define BAR_OFF (RP_OFF + 512)                  // flags[256]+go (memset 0 per launch)
#define PA_OFF (RP_OFF + 1024)                  // gram partials [64][15][256]
#define FP32_WS_FLOATS (PA_OFF + BSZ * 15 * NBLK)
// bf16 regions appended (byte offsets)
#define ZH_BYTE ((size_t)FP32_WS_FLOATS * 4)
#define ZL_BYTE (ZH_BYTE + (size_t)BSZ * DIM * 2)
#define WH_BYTE (ZL_BYTE + (size_t)BSZ * DIM * 2)
#define WL_BYTE (WH_BYTE + (size_t)DIM * DIM * 2)
#define WS_NEED (WL_BYTE + (size_t)DIM * DIM * 2)

typedef __attribute__((ext_vector_type(8))) short short8v;   // 8 bf16
typedef __attribute__((ext_vector_type(4))) float f32x4;

__device__ __forceinline__ unsigned short f2bf(float f) {
    unsigned int u = __float_as_uint(f);
    u = (u + 0x7fffu + ((u >> 16) & 1u)) >> 16;
    return (unsigned short)u;
}
__device__ __forceinline__ float bf2f(unsigned short h) {
    return __uint_as_float(((unsigned int)h) << 16);
}

// ---- zero-contention grid barrier (round-6, proven) ----
__device__ __forceinline__ void gridbar(unsigned int* flags, unsigned int* go,
                                        unsigned int e)
{
    __syncthreads();
    const int tid = threadIdx.x;
    if (blockIdx.x == 0) {
        if (tid == 0) {
            __builtin_amdgcn_fence(__ATOMIC_RELEASE, "agent");
            __hip_atomic_store(&flags[0], e, __ATOMIC_RELAXED,
                               __HIP_MEMORY_SCOPE_AGENT);
        }
        if (tid < NBLK) {
            while (__hip_atomic_load(&flags[tid], __ATOMIC_RELAXED,
                                     __HIP_MEMORY_SCOPE_AGENT) < e)
                __builtin_amdgcn_s_sleep(1);
        }
        __syncthreads();
        if (tid == 0) {
            __builtin_amdgcn_fence(__ATOMIC_ACQUIRE, "agent");
            __hip_atomic_store(go, e, __ATOMIC_RELAXED,
                               __HIP_MEMORY_SCOPE_AGENT);
        }
    } else {
        if (tid == 0) {
            __builtin_amdgcn_fence(__ATOMIC_RELEASE, "agent");
            __hip_atomic_store(&flags[blockIdx.x], e, __ATOMIC_RELAXED,
                               __HIP_MEMORY_SCOPE_AGENT);
            while (__hip_atomic_load(go, __ATOMIC_RELAXED,
                                     __HIP_MEMORY_SCOPE_AGENT) < e)
                __builtin_amdgcn_s_sleep(1);
            __builtin_amdgcn_fence(__ATOMIC_ACQUIRE, "agent");
        }
    }
    __syncthreads();
}

// ---------------- one-time W -> packed double-bf16 conversion ----------------
__device__ void convert_w(const float* __restrict__ W, unsigned short* __restrict__ Wh,
                          unsigned short* __restrict__ Wl, float* smem)
{
    const int tid = threadIdx.x;
    const int blk = blockIdx.x;
    const int jc = blk << 4;
    for (int sc = 0; sc < 8; ++sc) {
        __syncthreads();
        #pragma unroll
        for (int h = 0; h < 2; ++h) {
            int rrow = (tid >> 2) + (h << 8);
            int seg = tid & 3;
            float4 v = *(const float4*)&W[(size_t)((sc << 9) + rrow) * DIM + jc + (seg << 2)];
            float* dst = smem + rrow * 17 + (seg << 2);
            dst[0] = v.x; dst[1] = v.y; dst[2] = v.z; dst[3] = v.w;
        }
        __syncthreads();
        unsigned int* oh = (unsigned int*)(Wh + ((size_t)blk * 128 + sc * 16) * 512);
        unsigned int* ol = (unsigned int*)(Wl + ((size_t)blk * 128 + sc * 16) * 512);
        #pragma unroll
        for (int it = 0; it < 4; ++it) {
            int o = tid + (it << 10);
            int ksl = o >> 8, ln = (o >> 2) & 63, ep = o & 3;
            int kl = (ksl << 5) + ((ln >> 4) << 3) + (ep << 1);
            float w0 = smem[kl * 17 + (ln & 15)];
            float w1 = smem[(kl + 1) * 17 + (ln & 15)];
            unsigned short h0 = f2bf(w0), h1 = f2bf(w1);
            unsigned short l0 = f2bf(w0 - bf2f(h0)), l1 = f2bf(w1 - bf2f(h1));
            oh[o] = (unsigned int)h0 | ((unsigned int)h1 << 16);
            ol[o] = (unsigned int)l0 | ((unsigned int)l1 << 16);
        }
    }
    __syncthreads();
}

// ---- gram partials fused into GEMM epilogue ----
// Thread owns (row, col j); computes 15 products of g_i = (F-X)[row,i,j]
// (slot idx taken from registers), reduces over the 16-lane col group,
// lane cc==0 writes pa[row][e][blk]. Mask nn = active slots of NEXT body.
__device__ __forceinline__ void gram_partials(
    int row, int j, float fz, float zv, int idx, int nn,
    const float* __restrict__ Fs, const float* __restrict__ Xs,
    float* __restrict__ pa, int blk)
{
    float g[MEM];
    #pragma unroll
    for (int i = 0; i < MEM; ++i) {
        if (i < nn) {
            float fv = (i == idx) ? fz : Fs[(row * MEM + i) * DIM + j];
            float xv = (i == idx) ? zv : Xs[(row * MEM + i) * DIM + j];
            g[i] = fv - xv;
        } else {
            g[i] = 0.f;
        }
    }
    float pr[15];
    {
        int p = 0;
        #pragma unroll
        for (int i = 0; i < MEM; ++i)
            #pragma unroll
            for (int q = i; q < MEM; ++q) pr[p++] = g[i] * g[q];
    }
    #pragma unroll
    for (int off = 1; off < 16; off <<= 1)
        #pragma unroll
        for (int e = 0; e < 15; ++e) pr[e] += __shfl_xor(pr[e], off, 64);
    if ((threadIdx.x & 15) == 0) {
        #pragma unroll
        for (int e = 0; e < 15; ++e) pa[(row * 15 + e) * NBLK + blk] = pr[e];
    }
}

// ---------------- MFMA GEMM + tanh + gram partials + residual ----------------
__device__ __forceinline__ void gemm_tanh_mfma(
    int idx, int nn, const float* __restrict__ x, const float* __restrict__ bias,
    const unsigned short* __restrict__ Zh, const unsigned short* __restrict__ Zl,
    const unsigned short* __restrict__ Wh, const unsigned short* __restrict__ Wl,
    float* __restrict__ wsf, float* smem)
{
    const int tid = threadIdx.x;
    const int blk = blockIdx.x;
    const int lane = tid & 63;
    const int w = tid >> 6;
    const int r0 = lane & 15;
    const int kg = lane >> 4;
    float* Z = wsf + Z_OFF;
    float* Fs = wsf + F_OFF;
    float* Xs = wsf + X_OFF;
    float* rp = wsf + RP_OFF;
    float* pa = wsf + PA_OFF;
    f32x4 acc[4] = {f32x4{0,0,0,0}, f32x4{0,0,0,0}, f32x4{0,0,0,0}, f32x4{0,0,0,0}};

    const unsigned short* bh = Wh + (size_t)blk * 65536;
    const unsigned short* bl = Wl + (size_t)blk * 65536;
    const int ksbase = w << 3;

    short8v Bh[2], Bl[2], Ah[2][4], Al[2][4];
    {
        const int ks = ksbase;
        const int kbase = (ks << 5) + (kg << 3);
        Bh[0] = *(const short8v*)(bh + ((size_t)ks << 9) + (lane << 3));
        Bl[0] = *(const short8v*)(bl + ((size_t)ks << 9) + (lane << 3));
        #pragma unroll
        for (int m = 0; m < 4; ++m) {
            const size_t ao = (size_t)((m << 4) + r0) * DIM + kbase;
            Ah[0][m] = *(const short8v*)(Zh + ao);
            Al[0][m] = *(const short8v*)(Zl + ao);
        }
    }
    #pragma unroll
    for (int s = 0; s < 8; ++s) {
        const int cur = s & 1, nxt = cur ^ 1;
        if (s < 7) {
            const int ks = ksbase + s + 1;
            const int kbase = (ks << 5) + (kg << 3);
            Bh[nxt] = *(const short8v*)(bh + ((size_t)ks << 9) + (lane << 3));
            Bl[nxt] = *(const short8v*)(bl + ((size_t)ks << 9) + (lane << 3));
            #pragma unroll
            for (int m = 0; m < 4; ++m) {
                const size_t ao = (size_t)((m << 4) + r0) * DIM + kbase;
                Ah[nxt][m] = *(const short8v*)(Zh + ao);
                Al[nxt][m] = *(const short8v*)(Zl + ao);
            }
        }
        #pragma unroll
        for (int m = 0; m < 4; ++m) {
            acc[m] = __builtin_amdgcn_mfma_f32_16x16x32_bf16(Ah[cur][m], Bh[cur], acc[m], 0, 0, 0);
            acc[m] = __builtin_amdgcn_mfma_f32_16x16x32_bf16(Ah[cur][m], Bl[cur], acc[m], 0, 0, 0);
            acc[m] = __builtin_amdgcn_mfma_f32_16x16x32_bf16(Al[cur][m], Bh[cur], acc[m], 0, 0, 0);
        }
    }
    // cross-wave reduce: 2 rounds of 8 sections (stride 1028)
    const int row = tid >> 4, cc = tid & 15;
    const int m_o = row >> 4, rl = row & 15;
    const int lsrc = cc + ((rl >> 2) << 4), reg = rl & 3;
    float sum = 0.f;
    #pragma unroll
    for (int rnd = 0; rnd < 2; ++rnd) {
        __syncthreads();
        if ((w >> 3) == rnd) {
            float* sec = smem + (w & 7) * 1028;
            #pragma unroll
            for (int m = 0; m < 4; ++m)
                *(f32x4*)(sec + (m << 8) + (lane << 2)) = acc[m];
        }
        __syncthreads();
        #pragma unroll
        for (int p = 0; p < 8; ++p)
            sum += smem[p * 1028 + (m_o << 8) + (lsrc << 2) + reg];
    }
    // epilogue: tanh, F write, gram partials, residual partials
    const int j = (blk << 4) + cc;
    float fz = tanhf(sum + x[(row << 12) + j] + bias[j]);
    Fs[(row * MEM + idx) * DIM + j] = fz;
    float zv = Z[(row << 12) + j];
    gram_partials(row, j, fz, zv, idx, nn, Fs, Xs, pa, blk);
    float d = fz - zv;
    float lnum = d * d, lden = fz * fz;
    #pragma unroll
    for (int off = 1; off < 64; off <<= 1) {
        lnum += __shfl_xor(lnum, off, 64);
        lden += __shfl_xor(lden, off, 64);
    }
    if (lane == 0) { smem[8448 + w] = lnum; smem[8480 + w] = lden; }
    __syncthreads();
    if (tid == 0) {
        float a = 0.f, b2 = 0.f;
        #pragma unroll
        for (int i = 0; i < 16; ++i) { a += smem[8448 + i]; b2 += smem[8480 + i]; }
        rp[blk] = a;
        rp[NBLK + blk] = b2;
    }
}

// ---------------- fp32 fallback GEMM (round-2 core + new epilogue) ----------
__device__ __forceinline__ void gemm_tanh_fp32(
    int idx, int nn, const float* __restrict__ x, const float* __restrict__ W,
    const float* __restrict__ bias, float* __restrict__ wsf, float* smem)
{
    const int tid = threadIdx.x;
    const int blk = blockIdx.x;
    const int lane = tid & 63;
    const int w = tid >> 6;
    const int r = w >> 2;
    const int q = w & 3;
    const int jcq = (blk << 4) + (q << 2);
    float* Z = wsf + Z_OFF;
    float* Fs = wsf + F_OFF;
    float* Xs = wsf + X_OFF;
    float* rp = wsf + RP_OFF;
    float* pa = wsf + PA_OFF;

    float acc0 = 0.f, acc1 = 0.f, acc2 = 0.f, acc3 = 0.f;
    const int lx = lane & 15;
    const float* inrow = smem + (r << 12) + (lane << 6);
    const int srow = tid >> 4;
    const int sg = tid & 15;

    for (int step = 0; step < 16; ++step) {
        #pragma unroll
        for (int i = 0; i < 4; ++i) {
            float4 v = *(const float4*)&Z[srow * DIM + (i << 10) + (step << 6) + (sg << 2)];
            *(float4*)&smem[(i << 12) + (srow << 6) + ((sg ^ (srow & 15)) << 2)] = v;
        }
        __syncthreads();
        const float* wbase = W + (size_t)((r << 10) + (step << 6)) * DIM + jcq;
        #pragma unroll 2
        for (int s = 0; s < 16; ++s) {
            float4 in4 = *(const float4*)&inrow[(s ^ lx) << 2];
            const float* wr = wbase + (size_t)(s << 2) * DIM;
            #pragma unroll
            for (int t = 0; t < 4; ++t) {
                float iv = (t == 0) ? in4.x : (t == 1) ? in4.y : (t == 2) ? in4.z : in4.w;
                float4 wq = *(const float4*)(wr + (size_t)t * DIM);
                acc0 = fmaf(iv, wq.x, acc0);
                acc1 = fmaf(iv, wq.y, acc1);
                acc2 = fmaf(iv, wq.z, acc2);
                acc3 = fmaf(iv, wq.w, acc3);
            }
        }
        __syncthreads();
    }
    {
        float* rrow = smem + r * 1088 + lane * 17 + (q << 2);
        rrow[0] = acc0; rrow[1] = acc1; rrow[2] = acc2; rrow[3] = acc3;
    }
    __syncthreads();
    const int row = tid >> 4, cc = tid & 15;
    const int boff = row * 17 + cc;
    float sum = smem[boff] + smem[1088 + boff] + smem[2176 + boff] + smem[3264 + boff];
    const int j = (blk << 4) + cc;
    float fz = tanhf(sum + x[(row << 12) + j] + bias[j]);
    Fs[(row * MEM + idx) * DIM + j] = fz;
    float zv = Z[(row << 12) + j];
    gram_partials(row, j, fz, zv, idx, nn, Fs, Xs, pa, blk);
    float d = fz - zv;
    float lnum = d * d, lden = fz * fz;
    #pragma unroll
    for (int off = 1; off < 64; off <<= 1) {
        lnum += __shfl_xor(lnum, off, 64);
        lden += __shfl_xor(lden, off, 64);
    }
    if (lane == 0) { smem[8448 + w] = lnum; smem[8480 + w] = lden; }
    __syncthreads();
    if (tid == 0) {
        float a = 0.f, b2 = 0.f;
        for (int i = 0; i < 16; ++i) { a += smem[8448 + i]; b2 += smem[8480 + i]; }
        rp[blk] = a;
        rp[NBLK + blk] = b2;
    }
}

// ---------------- residual reduce (every block, deterministic) -----------
__device__ __forceinline__ float phase_res(const float* __restrict__ rp, float* smem)
{
    const int tid = threadIdx.x;
    const int lane = tid & 63, w = tid >> 6;
    float a = (tid < NBLK) ? rp[tid] : 0.f;
    float b = (tid < NBLK) ? rp[NBLK + tid] : 0.f;
    #pragma unroll
    for (int off = 1; off < 64; off <<= 1) {
        a += __shfl_xor(a, off, 64);
        b += __shfl_xor(b, off, 64);
    }
    if (lane == 0) { smem[w] = a; smem[16 + w] = b; }
    __syncthreads();
    if (tid == 0) {
        float sa = 0.f, sb = 0.f;
        for (int i = 0; i < 16; ++i) { sa += smem[i]; sb += smem[16 + i]; }
        smem[32] = sqrtf(sa) / (1e-5f + sqrtf(sb));
    }
    __syncthreads();
    float res = smem[32];
    __syncthreads();
    return res;
}

// ---- phase S: block b reduces pa[b], solves 6x6, combines row b ----
template <bool BF16>
__device__ void solve_combine_row(int b, int n, int idx, float* __restrict__ wsf,
                                  unsigned short* __restrict__ Zh,
                                  unsigned short* __restrict__ Zl, float* smem)
{
    const int tid = threadIdx.x;
    const int lane = tid & 63, w = tid >> 6;
    float* Xs = wsf + X_OFF;
    float* Fs = wsf + F_OFF;
    float* Z = wsf + Z_OFF;
    const float* pa = wsf + PA_OFF;

    // reduce 256 partials per gram entry: wave e handles entry e (fixed order)
    if (w < 15) {
        const float* src = pa + (b * 15 + w) * NBLK;
        f32x4 v = *(const f32x4*)&src[lane << 2];
        float s = ((v.x + v.y) + (v.z + v.w));
        #pragma unroll
        for (int off = 1; off < 64; off <<= 1) s += __shfl_xor(s, off, 64);
        if (lane == 0) smem[w] = s;
    }
    __syncthreads();
    if (tid == 0) {
        float G[MEM][MEM];
        int p = 0;
        for (int i = 0; i < MEM; ++i)
            for (int qq = i; qq < MEM; ++qq) {
                float v = smem[p++];
                G[i][qq] = v; G[qq][i] = v;
            }
        float H[6][6], yv[6];
        for (int i = 0; i < 6; ++i) yv[i] = (i == 0) ? 1.f : 0.f;
        H[0][0] = 0.f;
        for (int i = 0; i < MEM; ++i) {
            float mi = (i < n) ? 1.f : 0.f;
            H[0][1 + i] = mi;
            H[1 + i][0] = mi;
        }
        for (int i = 0; i < MEM; ++i)
            for (int qq = 0; qq < MEM; ++qq) {
                float v;
                if (i < n && qq < n) v = G[i][qq] + ((i == qq) ? LAM_ : 0.f);
                else v = (i == qq) ? 1.f : 0.f;
                H[1 + i][1 + qq] = v;
            }
        for (int col = 0; col < 6; ++col) {
            int piv = col;
            float mv = fabsf(H[col][col]);
            for (int rr = col + 1; rr < 6; ++rr) {
                float av = fabsf(H[rr][col]);
                if (av > mv) { mv = av; piv = rr; }
            }
            if (piv != col) {
                for (int c2 = 0; c2 < 6; ++c2) { float tv = H[col][c2]; H[col][c2] = H[piv][c2]; H[piv][c2] = tv; }
                float tv = yv[col]; yv[col] = yv[piv]; yv[piv] = tv;
            }
            float pv = H[col][col];
            for (int rr = col + 1; rr < 6; ++rr) {
                float f = H[rr][col] / pv;
                H[rr][col] = 0.f;
                for (int c2 = col + 1; c2 < 6; ++c2) H[rr][c2] -= f * H[col][c2];
                yv[rr] -= f * yv[col];
            }
        }
        float sol[6];
        for (int col = 5; col >= 0; --col) {
            float s = yv[col];
            for (int c2 = col + 1; c2 < 6; ++c2) s -= H[col][c2] * sol[c2];
            sol[col] = s / H[col][col];
        }
        for (int i = 0; i < MEM; ++i) smem[240 + i] = sol[1 + i];
    }
    __syncthreads();
    // combine row b over all 4096 cols: 1024 threads x 4
    float al[MEM];
    #pragma unroll
    for (int i = 0; i < MEM; ++i) al[i] = smem[240 + i];
    const int j4 = tid << 2;
    float4 zf = {0.f, 0.f, 0.f, 0.f};
    #pragma unroll
    for (int i = 0; i < MEM; ++i) {
        float4 fv = *(const float4*)&Fs[(b * MEM + i) * DIM + j4];
        zf.x = fmaf(al[i], fv.x, zf.x);
        zf.y = fmaf(al[i], fv.y, zf.y);
        zf.z = fmaf(al[i], fv.z, zf.z);
        zf.w = fmaf(al[i], fv.w, zf.w);
    }
    *(float4*)&Z[(b << 12) + j4] = zf;
    *(float4*)&Xs[(b * MEM + idx) * DIM + j4] = zf;
    if constexpr (BF16) {
        float zz[4] = {zf.x, zf.y, zf.z, zf.w};
        unsigned short h[4], l[4];
        #pragma unroll
        for (int c = 0; c < 4; ++c) {
            h[c] = f2bf(zz[c]);
            l[c] = f2bf(zz[c] - bf2f(h[c]));
        }
        unsigned int* zh32 = (unsigned int*)(Zh + ((size_t)b << 12) + j4);
        unsigned int* zl32 = (unsigned int*)(Zl + ((size_t)b << 12) + j4);
        zh32[0] = (unsigned int)h[0] | ((unsigned int)h[1] << 16);
        zh32[1] = (unsigned int)h[2] | ((unsigned int)h[3] << 16);
        zl32[0] = (unsigned int)l[0] | ((unsigned int)l[1] << 16);
        zl32[1] = (unsigned int)l[2] | ((unsigned int)l[3] << 16);
    }
}

// ---------------- persistent Anderson solver ----------------
template <bool BF16>
__global__ __launch_bounds__(NTHR, 4)
void deq_anderson(const float* __restrict__ x, const float* __restrict__ W,
                  const float* __restrict__ bias, float* __restrict__ out,
                  char* __restrict__ ws)
{
    __shared__ __align__(16) float smem[16384];  // 64 KB
    float* wsf = (float*)ws;
    unsigned int* flags = (unsigned int*)(wsf + BAR_OFF);
    unsigned int* go = flags + 320;
    unsigned short* Zh = (unsigned short*)(ws + ZH_BYTE);
    unsigned short* Zl = (unsigned short*)(ws + ZL_BYTE);
    unsigned short* Wh = (unsigned short*)(ws + WH_BYTE);
    unsigned short* Wl = (unsigned short*)(ws + WL_BYTE);
    const int tid = threadIdx.x;
    const int blk = blockIdx.x;
    const int e = blk * NTHR + tid;
    const int b = e >> 12, j = e & (DIM - 1);
    float* Xs = wsf + X_OFF;
    float* Fs = wsf + F_OFF;
    float* Z = wsf + Z_OFF;
    unsigned int ep = 1;

    // init: X[:,0]=0, X[:,1]=F0, F[:,0]=F0=tanh(x+b), Z=F0
    {
        float f0 = tanhf(x[e] + bias[j]);
        #pragma unroll
        for (int i = 0; i < MEM; ++i) {
            Xs[(b * MEM + i) * DIM + j] = (i == 1) ? f0 : 0.f;
            Fs[(b * MEM + i) * DIM + j] = (i == 0) ? f0 : 0.f;
        }
        Z[e] = f0;
        if constexpr (BF16) {
            unsigned short h = f2bf(f0);
            Zh[e] = h;
            Zl[e] = f2bf(f0 - bf2f(h));
        }
    }
    if constexpr (BF16) convert_w(W, Wh, Wl, smem);
    gridbar(flags, go, ep++);
    // F[:,1]=F1 GEMM; gram partials for body 2 (nn = min(2,5) = 2)
    if constexpr (BF16)
        gemm_tanh_mfma(1, 2, x, bias, Zh, Zl, Wh, Wl, wsf, smem);
    else
        gemm_tanh_fp32(1, 2, x, W, bias, wsf, smem);
    gridbar(flags, go, ep++);

    int kend = MAXIT;
    for (int k = 2; k < MAXIT; ++k) {
        float res = phase_res(wsf + RP_OFF, smem);   // uniform across grid
        if (k > 2 && res < TOL_) { kend = k; break; }
        const int n = (k < MEM) ? k : MEM;
        const int idx = k % MEM;
        const int nn = (k + 1 < MEM) ? (k + 1) : MEM;
        if (blk < BSZ) solve_combine_row<BF16>(blk, n, idx, wsf, Zh, Zl, smem);
        gridbar(flags, go, ep++);
        if constexpr (BF16)
            gemm_tanh_mfma(idx, nn, x, bias, Zh, Zl, Wh, Wl, wsf, smem);
        else
            gemm_tanh_fp32(idx, nn, x, W, bias, wsf, smem);
        gridbar(flags, go, ep++);
    }

    const int fidx = (kend - 1) % MEM;
    out[e] = Fs[(b * MEM + fidx) * DIM + j];
}

extern "C" void kernel_launch(void* const* d_in, const int* in_sizes, int n_in,
                              void* d_out, int out_size, void* d_ws, size_t ws_size,
                              hipStream_t stream)
{
    (void)in_sizes; (void)n_in; (void)out_size;
    if (ws_size < (size_t)FP32_WS_FLOATS * sizeof(float)) return;
    const float* x = (const float*)d_in[0];
    const float* W = (const float*)d_in[1];
    const float* b = (const float*)d_in[2];
    float* out = (float*)d_out;
    char* ws = (char*)d_ws;
    // zero flags[256] + go (robust to 0xAA poison; capture-legal)
    hipMemsetAsync(ws + (size_t)BAR_OFF * 4, 0, 2048, stream);
    void* args[] = {(void*)&x, (void*)&W, (void*)&b, (void*)&out, (void*)&ws};
    const void* fn = (ws_size >= WS_NEED)
                         ? reinterpret_cast<const void*>(&deq_anderson<true>)
                         : reinterpret_cast<const void*>(&deq_anderson<false>);
    hipLaunchCooperativeKernel(fn, dim3(NBLK), dim3(NTHR), args, 0, stream);
}

// Round 8
// 321.889 us; speedup vs baseline: 1.4096x; 1.4096x over previous
//
#include <hip/hip_runtime.h>

#define NBLK 256
#define GBLK 128            // active GEMM blocks (BN=32)
#define NTHR 1024
#define BSZ 64
#define DIM 4096
#define MEM 5
#define MAXIT 50
#define TOL_ 0.01f
#define LAM_ 1e-4f

// float-region workspace layout (float offsets)
#define X_OFF 0
#define F_OFF (BSZ * MEM * DIM)
#define Z_OFF (2 * BSZ * MEM * DIM)
#define RP_OFF (Z_OFF + BSZ * DIM)              // residual partials [2][256]
#define BAR_OFF (RP_OFF + 640)                  // flags[256]+go (memset 0 per launch)
#define FP32_WS_FLOATS (RP_OFF + 1024)
// bf16 regions appended (byte offsets)
#define ZH_BYTE ((size_t)(RP_OFF + 1024) * 4)
#define ZL_BYTE (ZH_BYTE + (size_t)BSZ * DIM * 2)
#define WH_BYTE (ZL_BYTE + (size_t)BSZ * DIM * 2)
#define WL_BYTE (WH_BYTE + (size_t)DIM * DIM * 2)
#define WS_NEED (WL_BYTE + (size_t)DIM * DIM * 2)

typedef __attribute__((ext_vector_type(8))) short short8v;   // 8 bf16
typedef __attribute__((ext_vector_type(4))) float f32x4;

__device__ __forceinline__ unsigned short f2bf(float f) {
    unsigned int u = __float_as_uint(f);
    u = (u + 0x7fffu + ((u >> 16) & 1u)) >> 16;
    return (unsigned short)u;
}
__device__ __forceinline__ float bf2f(unsigned short h) {
    return __uint_as_float(((unsigned int)h) << 16);
}

// ---- zero-contention grid barrier (round-6, proven) ----
__device__ __forceinline__ void gridbar(unsigned int* flags, unsigned int* go,
                                        unsigned int e)
{
    __syncthreads();
    const int tid = threadIdx.x;
    if (blockIdx.x == 0) {
        if (tid == 0) {
            __builtin_amdgcn_fence(__ATOMIC_RELEASE, "agent");
            __hip_atomic_store(&flags[0], e, __ATOMIC_RELAXED,
                               __HIP_MEMORY_SCOPE_AGENT);
        }
        if (tid < NBLK) {
            while (__hip_atomic_load(&flags[tid], __ATOMIC_RELAXED,
                                     __HIP_MEMORY_SCOPE_AGENT) < e)
                __builtin_amdgcn_s_sleep(1);
        }
        __syncthreads();
        if (tid == 0) {
            __builtin_amdgcn_fence(__ATOMIC_ACQUIRE, "agent");
            __hip_atomic_store(go, e, __ATOMIC_RELAXED,
                               __HIP_MEMORY_SCOPE_AGENT);
        }
    } else {
        if (tid == 0) {
            __builtin_amdgcn_fence(__ATOMIC_RELEASE, "agent");
            __hip_atomic_store(&flags[blockIdx.x], e, __ATOMIC_RELAXED,
                               __HIP_MEMORY_SCOPE_AGENT);
            while (__hip_atomic_load(go, __ATOMIC_RELAXED,
                                     __HIP_MEMORY_SCOPE_AGENT) < e)
                __builtin_amdgcn_s_sleep(1);
            __builtin_amdgcn_fence(__ATOMIC_ACQUIRE, "agent");
        }
    }
    __syncthreads();
}

// ---------------- one-time W -> packed double-bf16 conversion ----------------
// Layout per 16-col group ng: Wh[ng*65536 + ks*512 + lane*8 + e],
// k = ks*32 + (lane>>4)*8 + e, j = ng*16 + (lane&15).
__device__ void convert_w(const float* __restrict__ W, unsigned short* __restrict__ Wh,
                          unsigned short* __restrict__ Wl, float* smem)
{
    const int tid = threadIdx.x;
    const int blk = blockIdx.x;
    const int jc = blk << 4;
    for (int sc = 0; sc < 8; ++sc) {
        __syncthreads();
        #pragma unroll
        for (int h = 0; h < 2; ++h) {
            int rrow = (tid >> 2) + (h << 8);
            int seg = tid & 3;
            float4 v = *(const float4*)&W[(size_t)((sc << 9) + rrow) * DIM + jc + (seg << 2)];
            float* dst = smem + rrow * 17 + (seg << 2);
            dst[0] = v.x; dst[1] = v.y; dst[2] = v.z; dst[3] = v.w;
        }
        __syncthreads();
        unsigned int* oh = (unsigned int*)(Wh + ((size_t)blk * 128 + sc * 16) * 512);
        unsigned int* ol = (unsigned int*)(Wl + ((size_t)blk * 128 + sc * 16) * 512);
        #pragma unroll
        for (int it = 0; it < 4; ++it) {
            int o = tid + (it << 10);
            int ksl = o >> 8, ln = (o >> 2) & 63, ep = o & 3;
            int kl = (ksl << 5) + ((ln >> 4) << 3) + (ep << 1);
            float w0 = smem[kl * 17 + (ln & 15)];
            float w1 = smem[(kl + 1) * 17 + (ln & 15)];
            unsigned short h0 = f2bf(w0), h1 = f2bf(w1);
            unsigned short l0 = f2bf(w0 - bf2f(h0)), l1 = f2bf(w1 - bf2f(h1));
            oh[o] = (unsigned int)h0 | ((unsigned int)h1 << 16);
            ol[o] = (unsigned int)l0 | ((unsigned int)l1 << 16);
        }
    }
    __syncthreads();
}

// ---------------- MFMA GEMM + tanh + residual partials (BN=32) ----------------
// 128 active blocks x 32 cols; 16 waves K-split 16-way; each A-frag feeds
// 2 col-tiles in-register (halves A traffic vs BN=16).
__device__ __forceinline__ void gemm_tanh_mfma(
    int idx, const float* __restrict__ x, const float* __restrict__ bias,
    const unsigned short* __restrict__ Zh, const unsigned short* __restrict__ Zl,
    const unsigned short* __restrict__ Wh, const unsigned short* __restrict__ Wl,
    float* __restrict__ Z, float* __restrict__ Fs, float* __restrict__ rp, float* smem)
{
    const int tid = threadIdx.x;
    const int cb = blockIdx.x;              // 0..127
    const int lane = tid & 63;
    const int w = tid >> 6;                 // wave 0..15
    const int r0 = lane & 15;
    const int kg = lane >> 4;
    f32x4 acc[4][2] = {};

    const unsigned short* bh0 = Wh + (size_t)(cb * 2) * 65536;
    const unsigned short* bl0 = Wl + (size_t)(cb * 2) * 65536;
    const unsigned short* bh1 = Wh + (size_t)(cb * 2 + 1) * 65536;
    const unsigned short* bl1 = Wl + (size_t)(cb * 2 + 1) * 65536;
    const int ksbase = w << 3;

    #pragma unroll 2
    for (int s = 0; s < 8; ++s) {
        const int ks = ksbase + s;
        const size_t bo = ((size_t)ks << 9) + (lane << 3);
        short8v Bh0 = *(const short8v*)(bh0 + bo);
        short8v Bl0 = *(const short8v*)(bl0 + bo);
        short8v Bh1 = *(const short8v*)(bh1 + bo);
        short8v Bl1 = *(const short8v*)(bl1 + bo);
        const int kbase = (ks << 5) + (kg << 3);
        #pragma unroll
        for (int m = 0; m < 4; ++m) {
            const size_t ao = (size_t)((m << 4) + r0) * DIM + kbase;
            short8v Ah = *(const short8v*)(Zh + ao);
            short8v Al = *(const short8v*)(Zl + ao);
            acc[m][0] = __builtin_amdgcn_mfma_f32_16x16x32_bf16(Ah, Bh0, acc[m][0], 0, 0, 0);
            acc[m][0] = __builtin_amdgcn_mfma_f32_16x16x32_bf16(Ah, Bl0, acc[m][0], 0, 0, 0);
            acc[m][0] = __builtin_amdgcn_mfma_f32_16x16x32_bf16(Al, Bh0, acc[m][0], 0, 0, 0);
            acc[m][1] = __builtin_amdgcn_mfma_f32_16x16x32_bf16(Ah, Bh1, acc[m][1], 0, 0, 0);
            acc[m][1] = __builtin_amdgcn_mfma_f32_16x16x32_bf16(Ah, Bl1, acc[m][1], 0, 0, 0);
            acc[m][1] = __builtin_amdgcn_mfma_f32_16x16x32_bf16(Al, Bh1, acc[m][1], 0, 0, 0);
        }
    }
    // cross-wave reduce: 4 rounds of 4 sections; section = 2048 floats + pad 4
    const int row = tid >> 4, cc = tid & 15;
    const int m_o = row >> 4, rl = row & 15;
    const int lsrc = cc + ((rl >> 2) << 4), reg = rl & 3;
    float sum0 = 0.f, sum1 = 0.f;
    #pragma unroll
    for (int rnd = 0; rnd < 4; ++rnd) {
        __syncthreads();
        if ((w >> 2) == rnd) {
            float* sec = smem + (w & 3) * 2052;
            #pragma unroll
            for (int m = 0; m < 4; ++m) {
                *(f32x4*)(sec + ((m * 2 + 0) << 8) + (lane << 2)) = acc[m][0];
                *(f32x4*)(sec + ((m * 2 + 1) << 8) + (lane << 2)) = acc[m][1];
            }
        }
        __syncthreads();
        #pragma unroll
        for (int p = 0; p < 4; ++p) {
            sum0 += smem[p * 2052 + ((m_o * 2 + 0) << 8) + (lsrc << 2) + reg];
            sum1 += smem[p * 2052 + ((m_o * 2 + 1) << 8) + (lsrc << 2) + reg];
        }
    }
    // epilogue: tanh, F-slot write, residual partials (2 cols/thread)
    const int j0 = (cb << 5) + cc;
    const int j1 = j0 + 16;
    float fz0 = tanhf(sum0 + x[(row << 12) + j0] + bias[j0]);
    float fz1 = tanhf(sum1 + x[(row << 12) + j1] + bias[j1]);
    Fs[(row * MEM + idx) * DIM + j0] = fz0;
    Fs[(row * MEM + idx) * DIM + j1] = fz1;
    float d0 = fz0 - Z[(row << 12) + j0];
    float d1 = fz1 - Z[(row << 12) + j1];
    float lnum = d0 * d0 + d1 * d1;
    float lden = fz0 * fz0 + fz1 * fz1;
    #pragma unroll
    for (int off = 1; off < 64; off <<= 1) {
        lnum += __shfl_xor(lnum, off, 64);
        lden += __shfl_xor(lden, off, 64);
    }
    if (lane == 0) { smem[8448 + w] = lnum; smem[8480 + w] = lden; }
    __syncthreads();
    if (tid == 0) {
        float a = 0.f, b2 = 0.f;
        #pragma unroll
        for (int i = 0; i < 16; ++i) { a += smem[8448 + i]; b2 += smem[8480 + i]; }
        rp[cb] = a;
        rp[NBLK + cb] = b2;
    }
}

// ---------------- fp32 fallback GEMM (round-2, proven; 256 blocks) ----------
__device__ __forceinline__ void gemm_tanh_fp32(
    int idx, const float* __restrict__ x, const float* __restrict__ W,
    const float* __restrict__ bias, float* __restrict__ wsf, float* smem)
{
    const int tid = threadIdx.x;
    const int blk = blockIdx.x;
    const int lane = tid & 63;
    const int w = tid >> 6;
    const int r = w >> 2;
    const int q = w & 3;
    const int jcq = (blk << 4) + (q << 2);
    float* Z = wsf + Z_OFF;
    float* Fs = wsf + F_OFF;
    float* rp = wsf + RP_OFF;

    float acc0 = 0.f, acc1 = 0.f, acc2 = 0.f, acc3 = 0.f;
    const int lx = lane & 15;
    const float* inrow = smem + (r << 12) + (lane << 6);
    const int srow = tid >> 4;
    const int sg = tid & 15;

    for (int step = 0; step < 16; ++step) {
        #pragma unroll
        for (int i = 0; i < 4; ++i) {
            float4 v = *(const float4*)&Z[srow * DIM + (i << 10) + (step << 6) + (sg << 2)];
            *(float4*)&smem[(i << 12) + (srow << 6) + ((sg ^ (srow & 15)) << 2)] = v;
        }
        __syncthreads();
        const float* wbase = W + (size_t)((r << 10) + (step << 6)) * DIM + jcq;
        #pragma unroll 2
        for (int s = 0; s < 16; ++s) {
            float4 in4 = *(const float4*)&inrow[(s ^ lx) << 2];
            const float* wr = wbase + (size_t)(s << 2) * DIM;
            #pragma unroll
            for (int t = 0; t < 4; ++t) {
                float iv = (t == 0) ? in4.x : (t == 1) ? in4.y : (t == 2) ? in4.z : in4.w;
                float4 wq = *(const float4*)(wr + (size_t)t * DIM);
                acc0 = fmaf(iv, wq.x, acc0);
                acc1 = fmaf(iv, wq.y, acc1);
                acc2 = fmaf(iv, wq.z, acc2);
                acc3 = fmaf(iv, wq.w, acc3);
            }
        }
        __syncthreads();
    }
    {
        float* rrow = smem + r * 1088 + lane * 17 + (q << 2);
        rrow[0] = acc0; rrow[1] = acc1; rrow[2] = acc2; rrow[3] = acc3;
    }
    __syncthreads();
    const int row = tid >> 4, cc = tid & 15;
    const int boff = row * 17 + cc;
    float sum = smem[boff] + smem[1088 + boff] + smem[2176 + boff] + smem[3264 + boff];
    const int j = (blk << 4) + cc;
    float fz = tanhf(sum + x[(row << 12) + j] + bias[j]);
    Fs[(row * MEM + idx) * DIM + j] = fz;
    float d = fz - Z[(row << 12) + j];
    float lnum = d * d, lden = fz * fz;
    #pragma unroll
    for (int off = 1; off < 64; off <<= 1) {
        lnum += __shfl_xor(lnum, off, 64);
        lden += __shfl_xor(lden, off, 64);
    }
    if (lane == 0) { smem[8448 + w] = lnum; smem[8480 + w] = lden; }
    __syncthreads();
    if (tid == 0) {
        float a = 0.f, b2 = 0.f;
        for (int i = 0; i < 16; ++i) { a += smem[8448 + i]; b2 += smem[8480 + i]; }
        rp[blk] = a;
        rp[NBLK + blk] = b2;
    }
}

// ---------------- residual reduce (every block, deterministic) -----------
__device__ __forceinline__ float phase_res(const float* __restrict__ rp, float* smem)
{
    const int tid = threadIdx.x;
    const int lane = tid & 63, w = tid >> 6;
    float a = (tid < NBLK) ? rp[tid] : 0.f;
    float b = (tid < NBLK) ? rp[NBLK + tid] : 0.f;
    #pragma unroll
    for (int off = 1; off < 64; off <<= 1) {
        a += __shfl_xor(a, off, 64);
        b += __shfl_xor(b, off, 64);
    }
    if (lane == 0) { smem[w] = a; smem[16 + w] = b; }
    __syncthreads();
    if (tid == 0) {
        float sa = 0.f, sb = 0.f;
        for (int i = 0; i < 16; ++i) { sa += smem[i]; sb += smem[16 + i]; }
        smem[32] = sqrtf(sa) / (1e-5f + sqrtf(sb));
    }
    __syncthreads();
    float res = smem[32];
    __syncthreads();
    return res;
}

// ---- per-batch-row: Gram + 6x6 bordered solve + alpha-combine (round-6) ----
template <bool BF16>
__device__ void gram_solve_combine(int b, int n, int idx, float* __restrict__ wsf,
                                   unsigned short* __restrict__ Zh,
                                   unsigned short* __restrict__ Zl, float* smem)
{
    const int tid = threadIdx.x;
    const int lane = tid & 63, w = tid >> 6;
    float* Xs = wsf + X_OFF;
    float* Fs = wsf + F_OFF;
    float* Z = wsf + Z_OFF;
    const int j4 = tid << 2;

    float g[MEM][4];
    #pragma unroll
    for (int i = 0; i < MEM; ++i) {
        float4 fv = *(const float4*)&Fs[(b * MEM + i) * DIM + j4];
        float4 xv = *(const float4*)&Xs[(b * MEM + i) * DIM + j4];
        bool act = (i < n);
        g[i][0] = act ? (fv.x - xv.x) : 0.f;
        g[i][1] = act ? (fv.y - xv.y) : 0.f;
        g[i][2] = act ? (fv.z - xv.z) : 0.f;
        g[i][3] = act ? (fv.w - xv.w) : 0.f;
    }
    float gg[15];
    {
        int p = 0;
        #pragma unroll
        for (int i = 0; i < MEM; ++i)
            #pragma unroll
            for (int qq = i; qq < MEM; ++qq) {
                float s = 0.f;
                #pragma unroll
                for (int c = 0; c < 4; ++c) s = fmaf(g[i][c], g[qq][c], s);
                gg[p++] = s;
            }
    }
    #pragma unroll
    for (int off = 1; off < 64; off <<= 1)
        #pragma unroll
        for (int p = 0; p < 15; ++p) gg[p] += __shfl_xor(gg[p], off, 64);
    if (lane == 0) {
        #pragma unroll
        for (int p = 0; p < 15; ++p) smem[p * 16 + w] = gg[p];
    }
    __syncthreads();
    if (tid == 0) {
        float G[MEM][MEM];
        int p = 0;
        for (int i = 0; i < MEM; ++i)
            for (int qq = i; qq < MEM; ++qq) {
                float v = 0.f;
                for (int ww = 0; ww < 16; ++ww) v += smem[p * 16 + ww];
                G[i][qq] = v; G[qq][i] = v; ++p;
            }
        float H[6][6], yv[6];
        for (int i = 0; i < 6; ++i) yv[i] = (i == 0) ? 1.f : 0.f;
        H[0][0] = 0.f;
        for (int i = 0; i < MEM; ++i) {
            float mi = (i < n) ? 1.f : 0.f;
            H[0][1 + i] = mi;
            H[1 + i][0] = mi;
        }
        for (int i = 0; i < MEM; ++i)
            for (int qq = 0; qq < MEM; ++qq) {
                float v;
                if (i < n && qq < n) v = G[i][qq] + ((i == qq) ? LAM_ : 0.f);
                else v = (i == qq) ? 1.f : 0.f;
                H[1 + i][1 + qq] = v;
            }
        for (int col = 0; col < 6; ++col) {
            int piv = col;
            float mv = fabsf(H[col][col]);
            for (int rr = col + 1; rr < 6; ++rr) {
                float av = fabsf(H[rr][col]);
                if (av > mv) { mv = av; piv = rr; }
            }
            if (piv != col) {
                for (int c2 = 0; c2 < 6; ++c2) { float tv = H[col][c2]; H[col][c2] = H[piv][c2]; H[piv][c2] = tv; }
                float tv = yv[col]; yv[col] = yv[piv]; yv[piv] = tv;
            }
            float pv = H[col][col];
            for (int rr = col + 1; rr < 6; ++rr) {
                float f = H[rr][col] / pv;
                H[rr][col] = 0.f;
                for (int c2 = col + 1; c2 < 6; ++c2) H[rr][c2] -= f * H[col][c2];
                yv[rr] -= f * yv[col];
            }
        }
        float sol[6];
        for (int col = 5; col >= 0; --col) {
            float s = yv[col];
            for (int c2 = col + 1; c2 < 6; ++c2) s -= H[col][c2] * sol[c2];
            sol[col] = s / H[col][col];
        }
        for (int i = 0; i < MEM; ++i) smem[240 + i] = sol[1 + i];
    }
    __syncthreads();
    float al[MEM];
    #pragma unroll
    for (int i = 0; i < MEM; ++i) al[i] = smem[240 + i];
    float4 zf = {0.f, 0.f, 0.f, 0.f};
    #pragma unroll
    for (int i = 0; i < MEM; ++i) {
        float4 fv = *(const float4*)&Fs[(b * MEM + i) * DIM + j4];
        zf.x = fmaf(al[i], fv.x, zf.x);
        zf.y = fmaf(al[i], fv.y, zf.y);
        zf.z = fmaf(al[i], fv.z, zf.z);
        zf.w = fmaf(al[i], fv.w, zf.w);
    }
    *(float4*)&Z[(b << 12) + j4] = zf;
    *(float4*)&Xs[(b * MEM + idx) * DIM + j4] = zf;
    if constexpr (BF16) {
        float zz[4] = {zf.x, zf.y, zf.z, zf.w};
        unsigned short h[4], l[4];
        #pragma unroll
        for (int c = 0; c < 4; ++c) {
            h[c] = f2bf(zz[c]);
            l[c] = f2bf(zz[c] - bf2f(h[c]));
        }
        unsigned int* zh32 = (unsigned int*)(Zh + ((size_t)b << 12) + j4);
        unsigned int* zl32 = (unsigned int*)(Zl + ((size_t)b << 12) + j4);
        zh32[0] = (unsigned int)h[0] | ((unsigned int)h[1] << 16);
        zh32[1] = (unsigned int)h[2] | ((unsigned int)h[3] << 16);
        zl32[0] = (unsigned int)l[0] | ((unsigned int)l[1] << 16);
        zl32[1] = (unsigned int)l[2] | ((unsigned int)l[3] << 16);
    }
}

// ---------------- persistent Anderson solver ----------------
template <bool BF16>
__global__ __launch_bounds__(NTHR, 4)
void deq_anderson(const float* __restrict__ x, const float* __restrict__ W,
                  const float* __restrict__ bias, float* __restrict__ out,
                  char* __restrict__ ws)
{
    __shared__ __align__(16) float smem[16384];  // 64 KB
    float* wsf = (float*)ws;
    unsigned int* flags = (unsigned int*)(wsf + BAR_OFF);
    unsigned int* go = flags + 272;
    unsigned short* Zh = (unsigned short*)(ws + ZH_BYTE);
    unsigned short* Zl = (unsigned short*)(ws + ZL_BYTE);
    unsigned short* Wh = (unsigned short*)(ws + WH_BYTE);
    unsigned short* Wl = (unsigned short*)(ws + WL_BYTE);
    const int tid = threadIdx.x;
    const int blk = blockIdx.x;
    const int e = blk * NTHR + tid;
    const int b = e >> 12, j = e & (DIM - 1);
    float* Xs = wsf + X_OFF;
    float* Fs = wsf + F_OFF;
    float* Z = wsf + Z_OFF;
    float* rp = wsf + RP_OFF;
    unsigned int ep = 1;

    // init: X[:,0]=0, X[:,1]=F0, F[:,0]=F0=tanh(x+b), Z=F0
    {
        float f0 = tanhf(x[e] + bias[j]);
        #pragma unroll
        for (int i = 0; i < MEM; ++i) {
            Xs[(b * MEM + i) * DIM + j] = (i == 1) ? f0 : 0.f;
            Fs[(b * MEM + i) * DIM + j] = (i == 0) ? f0 : 0.f;
        }
        Z[e] = f0;
        if constexpr (BF16) {
            unsigned short h = f2bf(f0);
            Zh[e] = h;
            Zl[e] = f2bf(f0 - bf2f(h));
        }
    }
    if constexpr (BF16) convert_w(W, Wh, Wl, smem);
    gridbar(flags, go, ep++);
    if constexpr (BF16) {
        if (blk < GBLK)
            gemm_tanh_mfma(1, x, bias, Zh, Zl, Wh, Wl, Z, Fs, rp, smem);
        else if (tid == 0) { rp[blk] = 0.f; rp[NBLK + blk] = 0.f; }
    } else {
        gemm_tanh_fp32(1, x, W, bias, wsf, smem);
    }
    gridbar(flags, go, ep++);

    int kend = MAXIT;
    for (int k = 2; k < MAXIT; ++k) {
        float res = phase_res(rp, smem);
        if (k > 2 && res < TOL_) { kend = k; break; }
        const int n = (k < MEM) ? k : MEM;
        const int idx = k % MEM;
        if (blk < BSZ) gram_solve_combine<BF16>(blk, n, idx, wsf, Zh, Zl, smem);
        gridbar(flags, go, ep++);
        if constexpr (BF16) {
            if (blk < GBLK)
                gemm_tanh_mfma(idx, x, bias, Zh, Zl, Wh, Wl, Z, Fs, rp, smem);
        } else {
            gemm_tanh_fp32(idx, x, W, bias, wsf, smem);
        }
        gridbar(flags, go, ep++);
    }

    const int fidx = (kend - 1) % MEM;
    out[e] = Fs[(b * MEM + fidx) * DIM + j];
}

extern "C" void kernel_launch(void* const* d_in, const int* in_sizes, int n_in,
                              void* d_out, int out_size, void* d_ws, size_t ws_size,
                              hipStream_t stream)
{
    (void)in_sizes; (void)n_in; (void)out_size;
    if (ws_size < (size_t)FP32_WS_FLOATS * sizeof(float)) return;
    const float* x = (const float*)d_in[0];
    const float* W = (const float*)d_in[1];
    const float* b = (const float*)d_in[2];
    float* out = (float*)d_out;
    char* ws = (char*)d_ws;
    // zero flags[256] + go (robust to 0xAA poison; capture-legal)
    hipMemsetAsync(ws + (size_t)BAR_OFF * 4, 0, 1152, stream);
    void* args[] = {(void*)&x, (void*)&W, (void*)&b, (void*)&out, (void*)&ws};
    const void* fn = (ws_size >= WS_NEED)
                         ? reinterpret_cast<const void*>(&deq_anderson<true>)
                         : reinterpret_cast<const void*>(&deq_anderson<false>);
    hipLaunchCooperativeKernel(fn, dim3(NBLK), dim3(NTHR), args, 0, stream);
}

// Round 9
// 240.511 us; speedup vs baseline: 1.8865x; 1.3384x over previous
//
#include <hip/hip_runtime.h>

#define NBLK 256
#define GBLK 128            // active GEMM blocks (BN=32)
#define NTHR 1024
#define BSZ 64
#define DIM 4096
#define MEM 5
#define MAXIT 50
#define TOL_ 0.01f
#define LAM_ 1e-4f

// float-region workspace layout (float offsets)
#define X_OFF 0
#define F_OFF (BSZ * MEM * DIM)
#define Z_OFF (2 * BSZ * MEM * DIM)
#define RP_OFF (Z_OFF + BSZ * DIM)              // residual partials [2][256]
#define BAR_OFF (RP_OFF + 640)                  // flags[256]+go (memset 0 per launch)
#define FP32_WS_FLOATS (RP_OFF + 1024)
// fp16 regions appended (byte offsets)
#define ZF_BYTE ((size_t)(RP_OFF + 1024) * 4)
#define WF_BYTE (ZF_BYTE + (size_t)BSZ * DIM * 2)
#define WS_NEED (WF_BYTE + (size_t)DIM * DIM * 2)

typedef __attribute__((ext_vector_type(8))) _Float16 half8v;  // 8 fp16 (4 VGPRs)
typedef __attribute__((ext_vector_type(4))) float f32x4;

__device__ __forceinline__ unsigned short f2h(float f) {
    _Float16 h = (_Float16)f;           // RNE
    unsigned short u;
    __builtin_memcpy(&u, &h, 2);
    return u;
}

// ---- zero-contention grid barrier (round-6, proven) ----
__device__ __forceinline__ void gridbar(unsigned int* flags, unsigned int* go,
                                        unsigned int e)
{
    __syncthreads();
    const int tid = threadIdx.x;
    if (blockIdx.x == 0) {
        if (tid == 0) {
            __builtin_amdgcn_fence(__ATOMIC_RELEASE, "agent");
            __hip_atomic_store(&flags[0], e, __ATOMIC_RELAXED,
                               __HIP_MEMORY_SCOPE_AGENT);
        }
        if (tid < NBLK) {
            while (__hip_atomic_load(&flags[tid], __ATOMIC_RELAXED,
                                     __HIP_MEMORY_SCOPE_AGENT) < e)
                __builtin_amdgcn_s_sleep(1);
        }
        __syncthreads();
        if (tid == 0) {
            __builtin_amdgcn_fence(__ATOMIC_ACQUIRE, "agent");
            __hip_atomic_store(go, e, __ATOMIC_RELAXED,
                               __HIP_MEMORY_SCOPE_AGENT);
        }
    } else {
        if (tid == 0) {
            __builtin_amdgcn_fence(__ATOMIC_RELEASE, "agent");
            __hip_atomic_store(&flags[blockIdx.x], e, __ATOMIC_RELAXED,
                               __HIP_MEMORY_SCOPE_AGENT);
            while (__hip_atomic_load(go, __ATOMIC_RELAXED,
                                     __HIP_MEMORY_SCOPE_AGENT) < e)
                __builtin_amdgcn_s_sleep(1);
            __builtin_amdgcn_fence(__ATOMIC_ACQUIRE, "agent");
        }
    }
    __syncthreads();
}

// ---------------- one-time W -> packed fp16 conversion ----------------
// Layout per 16-col group ng: Wf[ng*65536 + ks*512 + lane*8 + e],
// k = ks*32 + (lane>>4)*8 + e, j = ng*16 + (lane&15).
__device__ void convert_w(const float* __restrict__ W, unsigned short* __restrict__ Wf,
                          float* smem)
{
    const int tid = threadIdx.x;
    const int blk = blockIdx.x;
    const int jc = blk << 4;
    for (int sc = 0; sc < 8; ++sc) {
        __syncthreads();
        #pragma unroll
        for (int h = 0; h < 2; ++h) {
            int rrow = (tid >> 2) + (h << 8);
            int seg = tid & 3;
            float4 v = *(const float4*)&W[(size_t)((sc << 9) + rrow) * DIM + jc + (seg << 2)];
            float* dst = smem + rrow * 17 + (seg << 2);
            dst[0] = v.x; dst[1] = v.y; dst[2] = v.z; dst[3] = v.w;
        }
        __syncthreads();
        unsigned int* of = (unsigned int*)(Wf + ((size_t)blk * 128 + sc * 16) * 512);
        #pragma unroll
        for (int it = 0; it < 4; ++it) {
            int o = tid + (it << 10);
            int ksl = o >> 8, ln = (o >> 2) & 63, ep = o & 3;
            int kl = (ksl << 5) + ((ln >> 4) << 3) + (ep << 1);
            float w0 = smem[kl * 17 + (ln & 15)];
            float w1 = smem[(kl + 1) * 17 + (ln & 15)];
            of[o] = (unsigned int)f2h(w0) | ((unsigned int)f2h(w1) << 16);
        }
    }
    __syncthreads();
}

// ---------------- fp16 MFMA GEMM + tanh + residual partials (BN=32) ----------
// 128 active blocks x 32 cols; 16 waves K-split 16-way; single-term fp16
// (fp16 11-bit mantissa: pre-tanh error ~1e-4, below trajectory noise).
__device__ __forceinline__ void gemm_tanh_mfma(
    int idx, const float* __restrict__ x, const float* __restrict__ bias,
    const unsigned short* __restrict__ Zf, const unsigned short* __restrict__ Wf,
    float* __restrict__ Z, float* __restrict__ Fs, float* __restrict__ rp, float* smem)
{
    const int tid = threadIdx.x;
    const int cb = blockIdx.x;              // 0..127
    const int lane = tid & 63;
    const int w = tid >> 6;                 // wave 0..15
    const int r0 = lane & 15;
    const int kg = lane >> 4;
    f32x4 acc[4][2] = {};

    const unsigned short* b0 = Wf + (size_t)(cb * 2) * 65536;
    const unsigned short* b1 = Wf + (size_t)(cb * 2 + 1) * 65536;
    const int ksbase = w << 3;

    #pragma unroll 2
    for (int s = 0; s < 8; ++s) {
        const int ks = ksbase + s;
        const size_t bo = ((size_t)ks << 9) + (lane << 3);
        half8v B0 = *(const half8v*)(b0 + bo);
        half8v B1 = *(const half8v*)(b1 + bo);
        const int kbase = (ks << 5) + (kg << 3);
        #pragma unroll
        for (int m = 0; m < 4; ++m) {
            const size_t ao = (size_t)((m << 4) + r0) * DIM + kbase;
            half8v Ah = *(const half8v*)(Zf + ao);
            acc[m][0] = __builtin_amdgcn_mfma_f32_16x16x32_f16(Ah, B0, acc[m][0], 0, 0, 0);
            acc[m][1] = __builtin_amdgcn_mfma_f32_16x16x32_f16(Ah, B1, acc[m][1], 0, 0, 0);
        }
    }
    // cross-wave reduce: 4 rounds of 4 sections; section = 2048 floats + pad 4
    const int row = tid >> 4, cc = tid & 15;
    const int m_o = row >> 4, rl = row & 15;
    const int lsrc = cc + ((rl >> 2) << 4), reg = rl & 3;
    float sum0 = 0.f, sum1 = 0.f;
    #pragma unroll
    for (int rnd = 0; rnd < 4; ++rnd) {
        __syncthreads();
        if ((w >> 2) == rnd) {
            float* sec = smem + (w & 3) * 2052;
            #pragma unroll
            for (int m = 0; m < 4; ++m) {
                *(f32x4*)(sec + ((m * 2 + 0) << 8) + (lane << 2)) = acc[m][0];
                *(f32x4*)(sec + ((m * 2 + 1) << 8) + (lane << 2)) = acc[m][1];
            }
        }
        __syncthreads();
        #pragma unroll
        for (int p = 0; p < 4; ++p) {
            sum0 += smem[p * 2052 + ((m_o * 2 + 0) << 8) + (lsrc << 2) + reg];
            sum1 += smem[p * 2052 + ((m_o * 2 + 1) << 8) + (lsrc << 2) + reg];
        }
    }
    // epilogue: tanh, F-slot write, residual partials (2 cols/thread)
    const int j0 = (cb << 5) + cc;
    const int j1 = j0 + 16;
    float fz0 = tanhf(sum0 + x[(row << 12) + j0] + bias[j0]);
    float fz1 = tanhf(sum1 + x[(row << 12) + j1] + bias[j1]);
    Fs[(row * MEM + idx) * DIM + j0] = fz0;
    Fs[(row * MEM + idx) * DIM + j1] = fz1;
    float d0 = fz0 - Z[(row << 12) + j0];
    float d1 = fz1 - Z[(row << 12) + j1];
    float lnum = d0 * d0 + d1 * d1;
    float lden = fz0 * fz0 + fz1 * fz1;
    #pragma unroll
    for (int off = 1; off < 64; off <<= 1) {
        lnum += __shfl_xor(lnum, off, 64);
        lden += __shfl_xor(lden, off, 64);
    }
    if (lane == 0) { smem[8448 + w] = lnum; smem[8480 + w] = lden; }
    __syncthreads();
    if (tid == 0) {
        float a = 0.f, b2 = 0.f;
        #pragma unroll
        for (int i = 0; i < 16; ++i) { a += smem[8448 + i]; b2 += smem[8480 + i]; }
        rp[cb] = a;
        rp[NBLK + cb] = b2;
    }
}

// ---------------- fp32 fallback GEMM (round-2, proven; 256 blocks) ----------
__device__ __forceinline__ void gemm_tanh_fp32(
    int idx, const float* __restrict__ x, const float* __restrict__ W,
    const float* __restrict__ bias, float* __restrict__ wsf, float* smem)
{
    const int tid = threadIdx.x;
    const int blk = blockIdx.x;
    const int lane = tid & 63;
    const int w = tid >> 6;
    const int r = w >> 2;
    const int q = w & 3;
    const int jcq = (blk << 4) + (q << 2);
    float* Z = wsf + Z_OFF;
    float* Fs = wsf + F_OFF;
    float* rp = wsf + RP_OFF;

    float acc0 = 0.f, acc1 = 0.f, acc2 = 0.f, acc3 = 0.f;
    const int lx = lane & 15;
    const float* inrow = smem + (r << 12) + (lane << 6);
    const int srow = tid >> 4;
    const int sg = tid & 15;

    for (int step = 0; step < 16; ++step) {
        #pragma unroll
        for (int i = 0; i < 4; ++i) {
            float4 v = *(const float4*)&Z[srow * DIM + (i << 10) + (step << 6) + (sg << 2)];
            *(float4*)&smem[(i << 12) + (srow << 6) + ((sg ^ (srow & 15)) << 2)] = v;
        }
        __syncthreads();
        const float* wbase = W + (size_t)((r << 10) + (step << 6)) * DIM + jcq;
        #pragma unroll 2
        for (int s = 0; s < 16; ++s) {
            float4 in4 = *(const float4*)&inrow[(s ^ lx) << 2];
            const float* wr = wbase + (size_t)(s << 2) * DIM;
            #pragma unroll
            for (int t = 0; t < 4; ++t) {
                float iv = (t == 0) ? in4.x : (t == 1) ? in4.y : (t == 2) ? in4.z : in4.w;
                float4 wq = *(const float4*)(wr + (size_t)t * DIM);
                acc0 = fmaf(iv, wq.x, acc0);
                acc1 = fmaf(iv, wq.y, acc1);
                acc2 = fmaf(iv, wq.z, acc2);
                acc3 = fmaf(iv, wq.w, acc3);
            }
        }
        __syncthreads();
    }
    {
        float* rrow = smem + r * 1088 + lane * 17 + (q << 2);
        rrow[0] = acc0; rrow[1] = acc1; rrow[2] = acc2; rrow[3] = acc3;
    }
    __syncthreads();
    const int row = tid >> 4, cc = tid & 15;
    const int boff = row * 17 + cc;
    float sum = smem[boff] + smem[1088 + boff] + smem[2176 + boff] + smem[3264 + boff];
    const int j = (blk << 4) + cc;
    float fz = tanhf(sum + x[(row << 12) + j] + bias[j]);
    Fs[(row * MEM + idx) * DIM + j] = fz;
    float d = fz - Z[(row << 12) + j];
    float lnum = d * d, lden = fz * fz;
    #pragma unroll
    for (int off = 1; off < 64; off <<= 1) {
        lnum += __shfl_xor(lnum, off, 64);
        lden += __shfl_xor(lden, off, 64);
    }
    if (lane == 0) { smem[8448 + w] = lnum; smem[8480 + w] = lden; }
    __syncthreads();
    if (tid == 0) {
        float a = 0.f, b2 = 0.f;
        for (int i = 0; i < 16; ++i) { a += smem[8448 + i]; b2 += smem[8480 + i]; }
        rp[blk] = a;
        rp[NBLK + blk] = b2;
    }
}

// ---------------- residual reduce (every block, deterministic) -----------
__device__ __forceinline__ float phase_res(const float* __restrict__ rp, float* smem)
{
    const int tid = threadIdx.x;
    const int lane = tid & 63, w = tid >> 6;
    float a = (tid < NBLK) ? rp[tid] : 0.f;
    float b = (tid < NBLK) ? rp[NBLK + tid] : 0.f;
    #pragma unroll
    for (int off = 1; off < 64; off <<= 1) {
        a += __shfl_xor(a, off, 64);
        b += __shfl_xor(b, off, 64);
    }
    if (lane == 0) { smem[w] = a; smem[16 + w] = b; }
    __syncthreads();
    if (tid == 0) {
        float sa = 0.f, sb = 0.f;
        for (int i = 0; i < 16; ++i) { sa += smem[i]; sb += smem[16 + i]; }
        smem[32] = sqrtf(sa) / (1e-5f + sqrtf(sb));
    }
    __syncthreads();
    float res = smem[32];
    __syncthreads();
    return res;
}

// ---- per-batch-row: Gram + 6x6 bordered solve + alpha-combine ----
template <bool F16>
__device__ void gram_solve_combine(int b, int n, int idx, float* __restrict__ wsf,
                                   unsigned short* __restrict__ Zf, float* smem)
{
    const int tid = threadIdx.x;
    const int lane = tid & 63, w = tid >> 6;
    float* Xs = wsf + X_OFF;
    float* Fs = wsf + F_OFF;
    float* Z = wsf + Z_OFF;
    const int j4 = tid << 2;

    float g[MEM][4];
    #pragma unroll
    for (int i = 0; i < MEM; ++i) {
        float4 fv = *(const float4*)&Fs[(b * MEM + i) * DIM + j4];
        float4 xv = *(const float4*)&Xs[(b * MEM + i) * DIM + j4];
        bool act = (i < n);
        g[i][0] = act ? (fv.x - xv.x) : 0.f;
        g[i][1] = act ? (fv.y - xv.y) : 0.f;
        g[i][2] = act ? (fv.z - xv.z) : 0.f;
        g[i][3] = act ? (fv.w - xv.w) : 0.f;
    }
    float gg[15];
    {
        int p = 0;
        #pragma unroll
        for (int i = 0; i < MEM; ++i)
            #pragma unroll
            for (int qq = i; qq < MEM; ++qq) {
                float s = 0.f;
                #pragma unroll
                for (int c = 0; c < 4; ++c) s = fmaf(g[i][c], g[qq][c], s);
                gg[p++] = s;
            }
    }
    #pragma unroll
    for (int off = 1; off < 64; off <<= 1)
        #pragma unroll
        for (int p = 0; p < 15; ++p) gg[p] += __shfl_xor(gg[p], off, 64);
    if (lane == 0) {
        #pragma unroll
        for (int p = 0; p < 15; ++p) smem[p * 16 + w] = gg[p];
    }
    __syncthreads();
    if (tid == 0) {
        float G[MEM][MEM];
        int p = 0;
        for (int i = 0; i < MEM; ++i)
            for (int qq = i; qq < MEM; ++qq) {
                float v = 0.f;
                for (int ww = 0; ww < 16; ++ww) v += smem[p * 16 + ww];
                G[i][qq] = v; G[qq][i] = v; ++p;
            }
        float H[6][6], yv[6];
        for (int i = 0; i < 6; ++i) yv[i] = (i == 0) ? 1.f : 0.f;
        H[0][0] = 0.f;
        for (int i = 0; i < MEM; ++i) {
            float mi = (i < n) ? 1.f : 0.f;
            H[0][1 + i] = mi;
            H[1 + i][0] = mi;
        }
        for (int i = 0; i < MEM; ++i)
            for (int qq = 0; qq < MEM; ++qq) {
                float v;
                if (i < n && qq < n) v = G[i][qq] + ((i == qq) ? LAM_ : 0.f);
                else v = (i == qq) ? 1.f : 0.f;
                H[1 + i][1 + qq] = v;
            }
        for (int col = 0; col < 6; ++col) {
            int piv = col;
            float mv = fabsf(H[col][col]);
            for (int rr = col + 1; rr < 6; ++rr) {
                float av = fabsf(H[rr][col]);
                if (av > mv) { mv = av; piv = rr; }
            }
            if (piv != col) {
                for (int c2 = 0; c2 < 6; ++c2) { float tv = H[col][c2]; H[col][c2] = H[piv][c2]; H[piv][c2] = tv; }
                float tv = yv[col]; yv[col] = yv[piv]; yv[piv] = tv;
            }
            float pv = H[col][col];
            for (int rr = col + 1; rr < 6; ++rr) {
                float f = H[rr][col] / pv;
                H[rr][col] = 0.f;
                for (int c2 = col + 1; c2 < 6; ++c2) H[rr][c2] -= f * H[col][c2];
                yv[rr] -= f * yv[col];
            }
        }
        float sol[6];
        for (int col = 5; col >= 0; --col) {
            float s = yv[col];
            for (int c2 = col + 1; c2 < 6; ++c2) s -= H[col][c2] * sol[c2];
            sol[col] = s / H[col][col];
        }
        for (int i = 0; i < MEM; ++i) smem[240 + i] = sol[1 + i];
    }
    __syncthreads();
    float al[MEM];
    #pragma unroll
    for (int i = 0; i < MEM; ++i) al[i] = smem[240 + i];
    float4 zf = {0.f, 0.f, 0.f, 0.f};
    #pragma unroll
    for (int i = 0; i < MEM; ++i) {
        float4 fv = *(const float4*)&Fs[(b * MEM + i) * DIM + j4];
        zf.x = fmaf(al[i], fv.x, zf.x);
        zf.y = fmaf(al[i], fv.y, zf.y);
        zf.z = fmaf(al[i], fv.z, zf.z);
        zf.w = fmaf(al[i], fv.w, zf.w);
    }
    *(float4*)&Z[(b << 12) + j4] = zf;
    *(float4*)&Xs[(b * MEM + idx) * DIM + j4] = zf;
    if constexpr (F16) {
        unsigned int* z16 = (unsigned int*)(Zf + ((size_t)b << 12) + j4);
        z16[0] = (unsigned int)f2h(zf.x) | ((unsigned int)f2h(zf.y) << 16);
        z16[1] = (unsigned int)f2h(zf.z) | ((unsigned int)f2h(zf.w) << 16);
    }
}

// ---------------- persistent Anderson solver ----------------
template <bool F16>
__global__ __launch_bounds__(NTHR, 4)
void deq_anderson(const float* __restrict__ x, const float* __restrict__ W,
                  const float* __restrict__ bias, float* __restrict__ out,
                  char* __restrict__ ws)
{
    __shared__ __align__(16) float smem[16384];  // 64 KB
    float* wsf = (float*)ws;
    unsigned int* flags = (unsigned int*)(wsf + BAR_OFF);
    unsigned int* go = flags + 272;
    unsigned short* Zf = (unsigned short*)(ws + ZF_BYTE);
    unsigned short* Wf = (unsigned short*)(ws + WF_BYTE);
    const int tid = threadIdx.x;
    const int blk = blockIdx.x;
    const int e = blk * NTHR + tid;
    const int b = e >> 12, j = e & (DIM - 1);
    float* Xs = wsf + X_OFF;
    float* Fs = wsf + F_OFF;
    float* Z = wsf + Z_OFF;
    float* rp = wsf + RP_OFF;
    unsigned int ep = 1;

    // init: X[:,0]=0, X[:,1]=F0, F[:,0]=F0=tanh(x+b), Z=F0
    {
        float f0 = tanhf(x[e] + bias[j]);
        #pragma unroll
        for (int i = 0; i < MEM; ++i) {
            Xs[(b * MEM + i) * DIM + j] = (i == 1) ? f0 : 0.f;
            Fs[(b * MEM + i) * DIM + j] = (i == 0) ? f0 : 0.f;
        }
        Z[e] = f0;
        if constexpr (F16) Zf[e] = f2h(f0);
    }
    if constexpr (F16) convert_w(W, Wf, smem);
    gridbar(flags, go, ep++);
    if constexpr (F16) {
        if (blk < GBLK)
            gemm_tanh_mfma(1, x, bias, Zf, Wf, Z, Fs, rp, smem);
        else if (tid == 0) { rp[blk] = 0.f; rp[NBLK + blk] = 0.f; }
    } else {
        gemm_tanh_fp32(1, x, W, bias, wsf, smem);
    }
    gridbar(flags, go, ep++);

    int kend = MAXIT;
    for (int k = 2; k < MAXIT; ++k) {
        float res = phase_res(rp, smem);
        if (k > 2 && res < TOL_) { kend = k; break; }
        const int n = (k < MEM) ? k : MEM;
        const int idx = k % MEM;
        if (blk < BSZ) gram_solve_combine<F16>(blk, n, idx, wsf, Zf, smem);
        gridbar(flags, go, ep++);
        if constexpr (F16) {
            if (blk < GBLK)
                gemm_tanh_mfma(idx, x, bias, Zf, Wf, Z, Fs, rp, smem);
        } else {
            gemm_tanh_fp32(idx, x, W, bias, wsf, smem);
        }
        gridbar(flags, go, ep++);
    }

    const int fidx = (kend - 1) % MEM;
    out[e] = Fs[(b * MEM + fidx) * DIM + j];
}

extern "C" void kernel_launch(void* const* d_in, const int* in_sizes, int n_in,
                              void* d_out, int out_size, void* d_ws, size_t ws_size,
                              hipStream_t stream)
{
    (void)in_sizes; (void)n_in; (void)out_size;
    if (ws_size < (size_t)FP32_WS_FLOATS * sizeof(float)) return;
    const float* x = (const float*)d_in[0];
    const float* W = (const float*)d_in[1];
    const float* b = (const float*)d_in[2];
    float* out = (float*)d_out;
    char* ws = (char*)d_ws;
    // zero flags[256] + go (robust to 0xAA poison; capture-legal)
    hipMemsetAsync(ws + (size_t)BAR_OFF * 4, 0, 1152, stream);
    void* args[] = {(void*)&x, (void*)&W, (void*)&b, (void*)&out, (void*)&ws};
    const void* fn = (ws_size >= WS_NEED)
                         ? reinterpret_cast<const void*>(&deq_anderson<true>)
                         : reinterpret_cast<const void*>(&deq_anderson<false>);
    hipLaunchCooperativeKernel(fn, dim3(NBLK), dim3(NTHR), args, 0, stream);
}